// Round 5
// baseline (393.503 us; speedup 1.0000x reference)
//
#include <hip/hip_runtime.h>

#define B_ 32
#define S_ 2048
#define H_ 1024
#define NCHUNK 128                // chunks per batch row; one wave per (b, chunk)
#define ROWS (S_ / NCHUNK)        // 16 s-rows per wave
#define KS 4                      // k-split for k_v

typedef __attribute__((ext_vector_type(4))) float f32x4;

// ---------------------------------------------------------------------------
// Kernel 1: vpart[ks][b][h] = sum_{k in ks*256..} h_t[b,k] * W[k,h]
// Each block: one (64-h x 256-k) W tile applied to ALL 32 batches -> W read
// exactly once (4 MB total, no redundancy). Block 256 = 4 subgroups x 64 h;
// subgroup `sub` accumulates batches sub*8..sub*8+7 (8 indep FMA chains).
// h_t chunk staged in LDS (32 b x 256 k = 32 KB), wave-broadcast reads.
__global__ __launch_bounds__(256) void k_v(const float* __restrict__ h_t,
                                           const float* __restrict__ W,
                                           float* __restrict__ vpart) {
    __shared__ float sh[32][256];
    int hb = blockIdx.x, ks = blockIdx.y;
    int t = threadIdx.x;
    int h_local = t & 63, sub = t >> 6;
    int h = hb * 64 + h_local;
    for (int i = t; i < 32 * 256; i += 256) {
        int b = i >> 8, k = i & 255;
        sh[b][k] = h_t[b * H_ + ks * 256 + k];
    }
    __syncthreads();
    float acc[8] = {0.f, 0.f, 0.f, 0.f, 0.f, 0.f, 0.f, 0.f};
    const float* wp = W + (size_t)(ks * 256) * H_ + h;
    #pragma unroll 4
    for (int k = 0; k < 256; ++k) {
        float w = wp[(size_t)k * H_];
        #pragma unroll
        for (int j = 0; j < 8; ++j)
            acc[j] = fmaf(sh[sub * 8 + j][k], w, acc[j]);
    }
    #pragma unroll
    for (int j = 0; j < 8; ++j) {
        int b = sub * 8 + j;
        vpart[((size_t)ks * B_ + b) * H_ + h] = acc[j];
    }
}

// ---------------------------------------------------------------------------
// Kernel 2: fused flash pass. One wave per (b, chunk); 4096 waves = 16/CU.
// Prefetch row s+1 while computing row s; nontemporal cntx loads (no reuse).
// Wave-uniform fast path: skip acc rescale when running max is unchanged.
__global__ __launch_bounds__(256, 4) void k_flash(const float* __restrict__ cntx,
                                                  const float* __restrict__ vpart,
                                                  float* __restrict__ partO,
                                                  float* __restrict__ stats) {
    int gw   = blockIdx.x * 4 + (threadIdx.x >> 6);   // wave id in [0, B_*NCHUNK)
    int lane = threadIdx.x & 63;
    int b    = gw >> 7;                                // NCHUNK = 128
    int ch   = gw & (NCHUNK - 1);

    // v fragment: vv[q] covers h = q*256 + lane*4 .. +3; sum KS k-split partials
    f32x4 vv[4];
    #pragma unroll
    for (int q = 0; q < 4; ++q) {
        f32x4 t0 = *(const f32x4*)(vpart + ((size_t)0 * B_ + b) * H_ + q * 256 + lane * 4);
        f32x4 t1 = *(const f32x4*)(vpart + ((size_t)1 * B_ + b) * H_ + q * 256 + lane * 4);
        f32x4 t2 = *(const f32x4*)(vpart + ((size_t)2 * B_ + b) * H_ + q * 256 + lane * 4);
        f32x4 t3 = *(const f32x4*)(vpart + ((size_t)3 * B_ + b) * H_ + q * 256 + lane * 4);
        vv[q] = (t0 + t1) + (t2 + t3);
    }

    const float* rp = cntx + ((size_t)b * S_ + (size_t)ch * ROWS) * H_ + lane * 4;
    f32x4 acc[4];
    #pragma unroll
    for (int q = 0; q < 4; ++q) acc[q] = (f32x4){0.f, 0.f, 0.f, 0.f};
    float m = -1e30f, l = 0.f;

    f32x4 cn[4];
    #pragma unroll
    for (int q = 0; q < 4; ++q)
        cn[q] = __builtin_nontemporal_load((const f32x4*)(rp + q * 256));

    for (int s = 0; s < ROWS; ++s) {
        f32x4 c[4];
        #pragma unroll
        for (int q = 0; q < 4; ++q) c[q] = cn[q];
        if (s + 1 < ROWS) {
            rp += H_;
            #pragma unroll
            for (int q = 0; q < 4; ++q)
                cn[q] = __builtin_nontemporal_load((const f32x4*)(rp + q * 256));
        }
        float d = 0.f;
        #pragma unroll
        for (int q = 0; q < 4; ++q)
            #pragma unroll
            for (int j = 0; j < 4; ++j) d = fmaf(c[q][j], vv[q][j], d);
        #pragma unroll
        for (int off = 32; off; off >>= 1) d += __shfl_xor(d, off);

        if (d > m) {                       // wave-uniform (d reduced across wave)
            float al = __expf(m - d);      // first iter: exp(-1e30-d)=0 kills stale acc
            m = d;                         // p = exp(d-m) = 1
            l = fmaf(l, al, 1.f);
            #pragma unroll
            for (int q = 0; q < 4; ++q)
                #pragma unroll
                for (int j = 0; j < 4; ++j)
                    acc[q][j] = fmaf(acc[q][j], al, c[q][j]);
        } else {                           // common path: no rescale
            float p = __expf(d - m);
            l += p;
            #pragma unroll
            for (int q = 0; q < 4; ++q)
                #pragma unroll
                for (int j = 0; j < 4; ++j)
                    acc[q][j] = fmaf(p, c[q][j], acc[q][j]);
        }
    }

    float* po = partO + (size_t)gw * H_;
    #pragma unroll
    for (int q = 0; q < 4; ++q) *(f32x4*)(po + q * 256 + lane * 4) = acc[q];
    if (lane == 0) { stats[gw * 2] = m; stats[gw * 2 + 1] = l; }
}

// ---------------------------------------------------------------------------
// Kernel 3: combine 128 chunk partials with their (m,l) stats + final blend.
// grid (B, H/256), block 256.
__global__ __launch_bounds__(256) void k_combine(const float* __restrict__ h_t,
                                                 const float* __restrict__ partO,
                                                 const float* __restrict__ stats,
                                                 const float* __restrict__ alpha,
                                                 const float* __restrict__ beta,
                                                 float* __restrict__ out) {
    int b = blockIdx.x, hb = blockIdx.y;
    int t = threadIdx.x;
    int wid = t >> 6;
    __shared__ float sw[NCHUNK];
    __shared__ float redm[2];
    __shared__ float reds[2];
    float mg = 0.f, lg = 0.f;
    if (t < NCHUNK) {                          // waves 0 and 1 exactly
        mg = stats[(b * NCHUNK + t) * 2];
        lg = stats[(b * NCHUNK + t) * 2 + 1];
        float M = mg;
        #pragma unroll
        for (int off = 32; off; off >>= 1) M = fmaxf(M, __shfl_xor(M, off));
        if ((t & 63) == 0) redm[wid] = M;
    }
    __syncthreads();
    float M = fmaxf(redm[0], redm[1]);
    if (t < NCHUNK) {
        float w = __expf(mg - M);
        sw[t] = w;
        float d = w * lg;
        #pragma unroll
        for (int off = 32; off; off >>= 1) d += __shfl_xor(d, off);
        if ((t & 63) == 0) reds[wid] = d;
    }
    __syncthreads();
    float den = reds[0] + reds[1];
    int h = hb * 256 + t;
    float sum = 0.f;
    #pragma unroll 16
    for (int g = 0; g < NCHUNK; ++g)
        sum = fmaf(sw[g], partO[(size_t)(b * NCHUNK + g) * H_ + h], sum);
    out[b * H_ + h] = fmaf(alpha[0], h_t[b * H_ + h], beta[0] * (sum / den));
}

// ---------------------------------------------------------------------------
extern "C" void kernel_launch(void* const* d_in, const int* in_sizes, int n_in,
                              void* d_out, int out_size, void* d_ws, size_t ws_size,
                              hipStream_t stream) {
    const float* h_t   = (const float*)d_in[0];
    const float* cntx  = (const float*)d_in[1];
    const float* W     = (const float*)d_in[2];
    const float* alpha = (const float*)d_in[3];
    const float* beta  = (const float*)d_in[4];
    float* out = (float*)d_out;

    float* vpart = (float*)d_ws;                        // KS*B_*H_     = 131072 floats
    float* partO = vpart + KS * B_ * H_;                // B_*NCHUNK*H_ = 4194304 floats
    float* stats = partO + (size_t)B_ * NCHUNK * H_;    // B_*NCHUNK*2  = 8192 floats

    k_v<<<dim3(H_ / 64, KS), 256, 0, stream>>>(h_t, W, vpart);
    k_flash<<<dim3(B_ * NCHUNK / 4), 256, 0, stream>>>(cntx, vpart, partO, stats);
    k_combine<<<dim3(B_, H_ / 256), 256, 0, stream>>>(h_t, partO, stats, alpha, beta, out);
}